// Round 10
// baseline (229.656 us; speedup 1.0000x reference)
//
#include <hip/hip_runtime.h>
#include <stdint.h>

// ---------- types / helpers ----------
typedef short bf16x8 __attribute__((ext_vector_type(8)));
typedef float f32x4 __attribute__((ext_vector_type(4)));

#define MFMA_BF16(a, b, c) __builtin_amdgcn_mfma_f32_16x16x32_bf16((a), (b), (c), 0, 0, 0)

__device__ __forceinline__ short f2bf(float x) {
  union { float f; uint32_t u; } v; v.f = x;
  uint32_t r = (v.u + 0x7FFFu + ((v.u >> 16) & 1u)) >> 16;  // RNE
  return (short)r;
}
__device__ __forceinline__ uint32_t rnd_bf_hi(float x) {  // RNE bits, bf16 in high half
  union { float f; uint32_t u; } v; v.f = x;
  return v.u + 0x7FFFu + ((v.u >> 16) & 1u);
}
__device__ __forceinline__ uint32_t pack2bf(float a, float b) {
  // exact RNE pack: D = [bf16(b) : bf16(a)]
  return __builtin_amdgcn_perm(rnd_bf_hi(b), rnd_bf_hi(a), 0x07060302);
}
__device__ __forceinline__ float bfbits2f(uint32_t b16) {
  union { uint32_t u; float f; } v; v.u = b16 << 16; return v.f;
}
__device__ __forceinline__ float fexp2(float x) {
#if __has_builtin(__builtin_amdgcn_exp2f)
  return __builtin_amdgcn_exp2f(x);
#else
  return __expf(x * 0.6931471805599453f);
#endif
}
__device__ __forceinline__ void async16(const void* g, void* l) {
  __builtin_amdgcn_global_load_lds(
      (const __attribute__((address_space(1))) uint32_t*)g,
      (__attribute__((address_space(3))) uint32_t*)l, 16, 0, 0);
}

// ---------- prep: fused fp32->bf16 casts + gates context GEMV ----------
__global__ __launch_bounds__(256) void prep_k(
    const float* __restrict__ x, const float* __restrict__ Wq,
    const float* __restrict__ Wk, const float* __restrict__ Wv,
    const float* __restrict__ Wo, const float* __restrict__ bq,
    short* __restrict__ xb, short* __restrict__ Wqb, short* __restrict__ Wkb,
    short* __restrict__ Wvb, short* __restrict__ Wob, float* __restrict__ ctx) {
  __shared__ float xs[1024];
  const int bid = blockIdx.x;
  const int tid = threadIdx.x;
  if (bid < 8192) {
    const float* src; short* dst; int idx;
    if (bid < 4096) {
      src = x; dst = xb; idx = (bid << 8) + tid;
    } else {
      const int r = bid - 4096;
      const int z = r >> 10;
      src = (z == 0) ? Wq : (z == 1) ? Wk : (z == 2) ? Wv : Wo;
      dst = (z == 0) ? Wqb : (z == 1) ? Wkb : (z == 2) ? Wvb : Wob;
      idx = ((r & 1023) << 8) + tid;
    }
    float4 v = ((const float4*)src)[idx];
    short4 o;
    o.x = f2bf(v.x); o.y = f2bf(v.y); o.z = f2bf(v.z); o.w = f2bf(v.w);
    ((short4*)dst)[idx] = o;
  } else {
    // gates context: ctx[b][n] = x[b,0,:] . Wq[n,:] + bq[n]   (fp32 exact path)
    const int r = bid - 8192;
    const int b = r >> 4;
    const int n0 = (r & 15) << 6;
    for (int i = tid; i < 1024; i += 256) xs[i] = x[b * 1048576 + i];
    __syncthreads();
    const int w = tid >> 6, lane = tid & 63;
    const float4* xv4 = (const float4*)xs;
    for (int rr = 0; rr < 16; ++rr) {
      const int n = n0 + (w << 4) + rr;
      const float4* wrow = (const float4*)(Wq + n * 1024);
      float p = 0.f;
#pragma unroll
      for (int c2 = 0; c2 < 4; ++c2) {
        float4 wv = wrow[lane + (c2 << 6)];
        float4 xv = xv4[lane + (c2 << 6)];
        p += xv.x * wv.x + xv.y * wv.y + xv.z * wv.z + xv.w * wv.w;
      }
#pragma unroll
      for (int off = 32; off; off >>= 1) p += __shfl_xor(p, off);
      if (lane == 0) ctx[b * 1024 + n] = p + bq[n];
    }
  }
}

// ---------- gates finisher: c, scale*log2e, u ----------
__global__ __launch_bounds__(256) void gates_fin(const float* __restrict__ ctx,
                                                 const float* __restrict__ Wg1,
                                                 const float* __restrict__ bg1,
                                                 const float* __restrict__ Wg2,
                                                 const float* __restrict__ bg2,
                                                 float* __restrict__ gates,
                                                 float* __restrict__ u_out) {
  __shared__ float red[16];
  const int tid = threadIdx.x, w = tid >> 6, lane = tid & 63;
  for (int b = 0; b < 4; ++b) {
    float4 cv = ((const float4*)(ctx + b * 1024))[tid];
    float4 w1 = ((const float4*)Wg1)[tid];
    float4 w2 = ((const float4*)Wg2)[tid];
    float p1 = cv.x * w1.x + cv.y * w1.y + cv.z * w1.z + cv.w * w1.w;
    float p2 = cv.x * w2.x + cv.y * w2.y + cv.z * w2.z + cv.w * w2.w;
#pragma unroll
    for (int off = 32; off; off >>= 1) { p1 += __shfl_xor(p1, off); p2 += __shfl_xor(p2, off); }
    if (lane == 0) { red[w] = p1; red[8 + w] = p2; }
    __syncthreads();
    if (tid == 0) {
      float g1 = red[0] + red[1] + red[2] + red[3] + bg1[0];
      float g2 = red[8] + red[9] + red[10] + red[11] + bg2[0];
      float q1 = 1.f / (1.f + expf(-g1));
      float q2 = 1.f / (1.f + expf(-g2));
      float c = fminf(fmaxf(q1 * q2, 1e-8f), 1.0f);
      gates[b * 2 + 0] = c;
      // (1/(sqrt(64)*tau)) * log2(e), applied to raw scores inside attn
      gates[b * 2 + 1] = (c < 0.3f ? c : 1.0f) * 0.125f * 1.4426950408889634f;
      u_out[b] = 1.0f - c;
    }
    __syncthreads();
  }
}

// ---------- QKV projection GEMM: 128x128 tile, BK=64, XOR-swizzled LDS ----------
// 16 K-iters x 32 MFMA per barrier-pair (half the barrier crossings of BK=32).
// C[m,n] = sum_k xb[m,k]*W[n,k] + bias[n];  z=0:Q  z=1:K  z=2:V^T [BH][64][T]
__global__ __launch_bounds__(256) void gemm_qkv(
    const short* __restrict__ xb,
    const short* __restrict__ Wqb, const short* __restrict__ Wkb, const short* __restrict__ Wvb,
    const float* __restrict__ bq, const float* __restrict__ bk, const float* __restrict__ bv,
    short* __restrict__ Qh, short* __restrict__ Kh, short* __restrict__ Vt) {
  const int z = blockIdx.z;
  const short* W = (z == 0) ? Wqb : (z == 1) ? Wkb : Wvb;
  const float* bias = (z == 0) ? bq : (z == 1) ? bk : bv;

  const int m0 = blockIdx.x << 7;
  const int n0 = blockIdx.y << 7;
  const int tid = threadIdx.x;
  const int w = tid >> 6, lane = tid & 63;
  const int m15 = lane & 15, quad = lane >> 4;
  const int wr = w >> 1, wc = w & 1;

  __shared__ short As[8192];   // 128 x 64, col-block(8) ^= row&7
  __shared__ short Bs[8192];

  f32x4 acc[4][4];
#pragma unroll
  for (int i = 0; i < 4; ++i)
#pragma unroll
    for (int j = 0; j < 4; ++j) { f32x4 zz = {0.f, 0.f, 0.f, 0.f}; acc[i][j] = zz; }

  // staging: 4 slots/thread; slot s: row = s>>3, physical cb = s&7, logical cb = pcb ^ (row&7)
  const short* gA[4];
  const short* gB[4];
  short* lA[4];
  short* lB[4];
#pragma unroll
  for (int i = 0; i < 4; ++i) {
    const int s = tid + (i << 8);
    const int row = s >> 3;
    const int cb = (s & 7) ^ (row & 7);
    gA[i] = xb + (m0 + row) * 1024 + (cb << 3);
    gB[i] = W + (n0 + row) * 1024 + (cb << 3);
    lA[i] = &As[s << 3];
    lB[i] = &Bs[s << 3];
  }

  for (int kt = 0; kt < 16; ++kt) {
#pragma unroll
    for (int i = 0; i < 4; ++i) { async16(gA[i], lA[i]); async16(gB[i], lB[i]); }
#pragma unroll
    for (int i = 0; i < 4; ++i) { gA[i] += 64; gB[i] += 64; }
    __syncthreads();
#pragma unroll
    for (int h = 0; h < 2; ++h) {
      bf16x8 a[4], b[4];
#pragma unroll
      for (int i = 0; i < 4; ++i) {
        const int ra = (wr << 6) + (i << 4) + m15;
        a[i] = *(const bf16x8*)(&As[(ra << 6) + ((((h << 2) + quad) ^ (ra & 7)) << 3)]);
      }
#pragma unroll
      for (int j = 0; j < 4; ++j) {
        const int rb = (wc << 6) + (j << 4) + m15;
        b[j] = *(const bf16x8*)(&Bs[(rb << 6) + ((((h << 2) + quad) ^ (rb & 7)) << 3)]);
      }
#pragma unroll
      for (int i = 0; i < 4; ++i)
#pragma unroll
        for (int j = 0; j < 4; ++j)
          acc[i][j] = MFMA_BF16(a[i], b[j], acc[i][j]);
    }
    __syncthreads();
  }

#pragma unroll
  for (int j = 0; j < 4; ++j) {
    const int n = n0 + (wc << 6) + (j << 4) + m15;
    const float bb_ = bias[n];
    const int h = n >> 6, dk = n & 63;
#pragma unroll
    for (int i = 0; i < 4; ++i) {
      const int mb = m0 + (wr << 6) + (i << 4) + (quad << 2);
#pragma unroll
      for (int r = 0; r < 4; ++r) {
        const int m = mb + r;
        const int batch = m >> 10, t = m & 1023;
        const short o = f2bf(acc[i][j][r] + bb_);
        if (z == 2) {
          Vt[((batch * 16 + h) * 64 + dk) * 1024 + t] = o;        // [BH][64][T]
        } else if (z == 1) {
          Kh[((batch * 16 + h) * 1024 + t) * 64 + dk] = o;        // [BH][T][64]
        } else {
          Qh[((batch * 16 + h) * 1024 + t) * 64 + dk] = o;
        }
      }
    }
  }
}

// ---------- output projection GEMM: 64x128, m97 2-barrier, swizzled, fp32 out ----------
// UNCHANGED from R7 — serves as session clock canary (~14 us healthy).
__global__ __launch_bounds__(256) void gemm_out(const short* __restrict__ Ab,
                                                const short* __restrict__ Wo,
                                                const float* __restrict__ bo,
                                                float* __restrict__ Cout) {
  const int m0 = blockIdx.x << 6;
  const int n0 = blockIdx.y << 7;
  const int tid = threadIdx.x;
  const int w = tid >> 6, lane = tid & 63;
  const int m15 = lane & 15, quad = lane >> 4;
  const int wr = w >> 1, wc = w & 1;

  __shared__ short As[2048];   // 64 x 32, swizzled
  __shared__ short Bs[4096];   // 128 x 32, swizzled

  f32x4 acc[2][4];
#pragma unroll
  for (int i = 0; i < 2; ++i)
#pragma unroll
    for (int j = 0; j < 4; ++j) { f32x4 zz = {0.f, 0.f, 0.f, 0.f}; acc[i][j] = zz; }

  const int s0 = tid, s1 = tid + 256;
  const int arow = s0 >> 2, alcb = (s0 & 3) ^ ((arow >> 1) & 3);
  const int brow1 = s1 >> 2, blcb1 = (s1 & 3) ^ ((brow1 >> 1) & 3);
  const short* gA  = Ab + (m0 + arow) * 1024 + (alcb << 3);
  const short* gB0 = Wo + (n0 + arow) * 1024 + (alcb << 3);
  const short* gB1 = Wo + (n0 + brow1) * 1024 + (blcb1 << 3);
  short* lA  = &As[s0 << 3];
  short* lB0 = &Bs[s0 << 3];
  short* lB1 = &Bs[s1 << 3];

  for (int kt = 0; kt < 32; ++kt) {
    async16(gA, lA);
    async16(gB0, lB0); async16(gB1, lB1);
    gA += 32; gB0 += 32; gB1 += 32;
    __syncthreads();
    bf16x8 a[2], b[4];
#pragma unroll
    for (int i = 0; i < 2; ++i) {
      const int ra = (wr << 5) + (i << 4) + m15;
      a[i] = *(const bf16x8*)(&As[ra * 32 + ((quad ^ ((ra >> 1) & 3)) << 3)]);
    }
#pragma unroll
    for (int j = 0; j < 4; ++j) {
      const int rb = (wc << 6) + (j << 4) + m15;
      b[j] = *(const bf16x8*)(&Bs[rb * 32 + ((quad ^ ((rb >> 1) & 3)) << 3)]);
    }
#pragma unroll
    for (int i = 0; i < 2; ++i)
#pragma unroll
      for (int j = 0; j < 4; ++j)
        acc[i][j] = MFMA_BF16(a[i], b[j], acc[i][j]);
    __syncthreads();
  }

#pragma unroll
  for (int j = 0; j < 4; ++j) {
    const int n = n0 + (wc << 6) + (j << 4) + m15;
    const float bb_ = bo[n];
#pragma unroll
    for (int i = 0; i < 2; ++i) {
      const int mb = m0 + (wr << 5) + (i << 4) + (quad << 2);
#pragma unroll
      for (int r = 0; r < 4; ++r)
        Cout[(mb + r) * 1024 + n] = acc[i][j][r] + bb_;
    }
  }
}

// ---------- meanV over keys: mV[bh][d] = sum_t Vt[bh][d][t]  (raw sum) ----------
__global__ __launch_bounds__(256) void meanv_k(const short* __restrict__ Vt,
                                               float* __restrict__ mV) {
  const int bh = blockIdx.x;
  const int tid = threadIdx.x;
  const int d = tid >> 2, part = tid & 3;
  const short* row = Vt + bh * 65536 + d * 1024 + part * 256;
  float s = 0.f;
#pragma unroll 4
  for (int i = 0; i < 64; ++i) {
    uint2 v = *(const uint2*)(row + i * 4);
    s += bfbits2f(v.x & 0xffffu) + bfbits2f(v.x >> 16) +
         bfbits2f(v.y & 0xffffu) + bfbits2f(v.y >> 16);
  }
  s += __shfl_xor(s, 1);
  s += __shfl_xor(s, 2);
  if (part == 0) mV[bh * 64 + d] = s;
}

// ---------- flash attention: 512-thread block, kv split across wave-groups ----------
// Group g (waves 4g..4g+3) handles kv tiles 8g..8g+7 with R7's exact iteration
// body; merge via LDS (fp32 O^T stride-68 + partial l), group 0 does epilogue.
__global__ __launch_bounds__(512, 6) void attn_k(const short* __restrict__ Qh,
                                                 const short* __restrict__ Kh,
                                                 const short* __restrict__ Vt,
                                                 const float* __restrict__ gates,
                                                 const float* __restrict__ mV,
                                                 short* __restrict__ attnb) {
  const int bh = blockIdx.x;
  const int b = bh >> 4, h = bh & 15;
  const int q0 = blockIdx.y << 6;
  const int tid = threadIdx.x;
  const int g = tid >> 8;          // kv-half group
  const int t8 = tid & 255;
  const int w = t8 >> 6, lane = t8 & 63;
  const int m15 = lane & 15, quad = lane >> 4;

  __shared__ short KV[2][8192];    // [g][ Ks 4096 | Vs 4096 ], row&7 XOR swizzle
  __shared__ float l1s[64];

  short* Ks = &KV[g][0];
  short* Vs = &KV[g][4096];

  const short* ksrc = Kh + bh * 65536;
  const short* vsrc = Vt + bh * 65536;
  const float sl = gates[b * 2 + 1];

  // hoisted Q B-fragments (wave's 16 q-cols, loop-invariant)
  const short* qsrc = Qh + ((bh << 10) + q0 + (w << 4) + m15) * 64;
  const bf16x8 qb0 = *(const bf16x8*)(qsrc + (quad << 3));
  const bf16x8 qb1 = *(const bf16x8*)(qsrc + 32 + (quad << 3));

  // staging addresses (lane-linear LDS dest as global_load_lds requires)
  const int off0 = t8, off1 = t8 + 256;
  const int r0 = off0 >> 3, cb0 = (off0 & 7) ^ (r0 & 7);
  const int r1 = off1 >> 3, cb1 = (off1 & 7) ^ (r1 & 7);

  float lsum = 0.f;
  f32x4 o_acc[4];
#pragma unroll
  for (int jd = 0; jd < 4; ++jd) { f32x4 zz = {0.f, 0.f, 0.f, 0.f}; o_acc[jd] = zz; }

  const int srcA = ((quad & 1) << 5) + m15;  // source quad 2*(qt&1)
  const int srcB = srcA + 16;                // source quad 2*(qt&1)+1
  const bool selhi = (quad & 2) != 0;        // s = 2H + (quad>>1)

  for (int kv = 0; kv < 8; ++kv) {
    const int kt = (g << 3) + kv;
    async16(ksrc + ((kt << 6) + r0) * 64 + (cb0 << 3), Ks + (off0 << 3));
    async16(ksrc + ((kt << 6) + r1) * 64 + (cb1 << 3), Ks + (off1 << 3));
    async16(vsrc + r0 * 1024 + (kt << 6) + (cb0 << 3), Vs + (off0 << 3));
    async16(vsrc + r1 * 1024 + (kt << 6) + (cb1 << 3), Vs + (off1 << 3));
    __syncthreads();  // drains the async16s (vmcnt) for all waves

    // S^T tile: lane holds (q = w*16+m15, k = kt*64 + s*16 + quad*4 + r)
    f32x4 sacc[4];
#pragma unroll
    for (int s = 0; s < 4; ++s) {
      const int row = (s << 4) + m15;
      const int sw = row & 7;
      bf16x8 a0 = *(const bf16x8*)(Ks + (row << 6) + ((quad ^ sw) << 3));
      bf16x8 a1 = *(const bf16x8*)(Ks + (row << 6) + (((quad + 4) ^ sw) << 3));
      f32x4 zz = {0.f, 0.f, 0.f, 0.f};
      zz = MFMA_BF16(a0, qb0, zz);
      zz = MFMA_BF16(a1, qb1, zz);
      sacc[s] = zz;
    }

    // lane-local softmax numerators + packed bf16 pairs (exact RNE)
    uint32_t pk[4][2];
#pragma unroll
    for (int s = 0; s < 4; ++s) {
      float p0 = fexp2(sacc[s][0] * sl);
      float p1 = fexp2(sacc[s][1] * sl);
      float p2 = fexp2(sacc[s][2] * sl);
      float p3 = fexp2(sacc[s][3] * sl);
      lsum += (p0 + p1) + (p2 + p3);
      pk[s][0] = pack2bf(p0, p1);
      pk[s][1] = pack2bf(p2, p3);
    }

    // build P B-fragments: lane n=q needs k = H*32 + quad*8 + j
    bf16x8 pf[2];
#pragma unroll
    for (int H = 0; H < 2; ++H) {
      uint32_t f[4];
#pragma unroll
      for (int rp = 0; rp < 2; ++rp) {
        uint32_t alo = (uint32_t)__shfl((int)pk[2 * H][rp], srcA);
        uint32_t ahi = (uint32_t)__shfl((int)pk[2 * H + 1][rp], srcA);
        uint32_t blo = (uint32_t)__shfl((int)pk[2 * H][rp], srcB);
        uint32_t bhi = (uint32_t)__shfl((int)pk[2 * H + 1][rp], srcB);
        f[rp]     = selhi ? ahi : alo;
        f[2 + rp] = selhi ? bhi : blo;
      }
      pf[H] = *(bf16x8*)f;
    }

    // O^T += V^T * P
#pragma unroll
    for (int jd = 0; jd < 4; ++jd) {
      const int row = (jd << 4) + m15;
      const int sw = row & 7;
      bf16x8 v0 = *(const bf16x8*)(Vs + (row << 6) + ((quad ^ sw) << 3));
      bf16x8 v1 = *(const bf16x8*)(Vs + (row << 6) + (((quad + 4) ^ sw) << 3));
      o_acc[jd] = MFMA_BF16(v0, pf[0], o_acc[jd]);
      o_acc[jd] = MFMA_BF16(v1, pf[1], o_acc[jd]);
    }
    __syncthreads();  // all waves done reading Ks/Vs before next staging
  }

  // partial l(q): reduce over quads within each group's wave
  float l = lsum;
  l += __shfl_xor(l, 16);
  l += __shfl_xor(l, 32);

  // merge: group 1 dumps fp32 O^T (stride 68: aligned b128, 2-way banks) + l
  float* Ops = (float*)&KV[0][0];  // 64*68*4B = 17408 B <= 32768 B, reuse staging
  const int q = (w << 4) + m15;
  if (g == 1) {
#pragma unroll
    for (int jd = 0; jd < 4; ++jd)
      *(f32x4*)&Ops[q * 68 + (jd << 4) + (quad << 2)] = o_acc[jd];
    if (quad == 0) l1s[q] = l;
  }
  __syncthreads();
  if (g == 0) {
    const float lt = l + l1s[q];
    const float cg = gates[b * 2 + 0];
    const float s0 = cg / lt;
    const float coef = (1.0f - cg) * (1.0f / 1024.0f);  // mV holds raw sums
    short* orow = attnb + ((b << 10) + q0 + q) * 1024 + (h << 6);
#pragma unroll
    for (int jd = 0; jd < 4; ++jd) {
      f32x4 o1 = *(const f32x4*)&Ops[q * 68 + (jd << 4) + (quad << 2)];
      float4 mv = *(const float4*)(mV + (bh << 6) + (jd << 4) + (quad << 2));
      float v0_ = s0 * (o_acc[jd][0] + o1[0]) + coef * mv.x;
      float v1_ = s0 * (o_acc[jd][1] + o1[1]) + coef * mv.y;
      float v2_ = s0 * (o_acc[jd][2] + o1[2]) + coef * mv.z;
      float v3_ = s0 * (o_acc[jd][3] + o1[3]) + coef * mv.w;
      uint2 st;
      st.x = pack2bf(v0_, v1_);
      st.y = pack2bf(v2_, v3_);
      *(uint2*)(orow + (jd << 4) + (quad << 2)) = st;
    }
  }
}

// ---------- launch ----------
extern "C" void kernel_launch(void* const* d_in, const int* in_sizes, int n_in,
                              void* d_out, int out_size, void* d_ws, size_t ws_size,
                              hipStream_t stream) {
  const float* x   = (const float*)d_in[0];
  const float* Wq  = (const float*)d_in[1];
  const float* bq  = (const float*)d_in[2];
  const float* Wk  = (const float*)d_in[3];
  const float* bk  = (const float*)d_in[4];
  const float* Wv  = (const float*)d_in[5];
  const float* bv  = (const float*)d_in[6];
  const float* Wo  = (const float*)d_in[7];
  const float* bo  = (const float*)d_in[8];
  const float* Wg1 = (const float*)d_in[9];
  const float* bg1 = (const float*)d_in[10];
  const float* Wg2 = (const float*)d_in[11];
  const float* bg2 = (const float*)d_in[12];
  float* out = (float*)d_out;

  char* ws = (char*)d_ws;
  short* xb   = (short*)(ws + 0);          //  8 MB  x bf16 [4096][1024]
  short* Wqb  = (short*)(ws + 8388608);    //  2 MB
  short* Wkb  = (short*)(ws + 10485760);   //  2 MB
  short* Wvb  = (short*)(ws + 12582912);   //  2 MB
  short* Wob  = (short*)(ws + 14680064);   //  2 MB
  short* Qh   = (short*)(ws + 16777216);   //  8 MB  [BH][T][64]
  short* Kh   = (short*)(ws + 25165824);   //  8 MB  [BH][T][64]
  short* Vt   = (short*)(ws + 33554432);   //  8 MB  [BH][64][T]
  short* attb = (short*)(ws + 41943040);   //  8 MB  [4096][1024]
  float* ctx  = (float*)(ws + 50331648);   // 16 KB
  float* gat  = (float*)(ws + 50348032);   // 32 B   [B][{c, scale*log2e}]
  float* mV   = (float*)(ws + 50348064);   // 16 KB  [BH][64] raw sums

  prep_k<<<8256, 256, 0, stream>>>(x, Wq, Wk, Wv, Wo, bq,
                                   xb, Wqb, Wkb, Wvb, Wob, ctx);
  gates_fin<<<1, 256, 0, stream>>>(ctx, Wg1, bg1, Wg2, bg2, gat, out + 4194304);

  gemm_qkv<<<dim3(32, 8, 3), 256, 0, stream>>>(xb, Wqb, Wkb, Wvb, bq, bk, bv,
                                               Qh, Kh, Vt);
  meanv_k<<<64, 256, 0, stream>>>(Vt, mV);
  attn_k<<<dim3(64, 16), 512, 0, stream>>>(Qh, Kh, Vt, gat, mV, attb);
  gemm_out<<<dim3(64, 8), 256, 0, stream>>>(attb, Wob, bo, out);
}

// Round 11
// 212.716 us; speedup vs baseline: 1.0796x; 1.0796x over previous
//
#include <hip/hip_runtime.h>
#include <stdint.h>

// ---------- types / helpers ----------
typedef short bf16x8 __attribute__((ext_vector_type(8)));
typedef float f32x4 __attribute__((ext_vector_type(4)));

#define MFMA_BF16(a, b, c) __builtin_amdgcn_mfma_f32_16x16x32_bf16((a), (b), (c), 0, 0, 0)

__device__ __forceinline__ short f2bf(float x) {
  union { float f; uint32_t u; } v; v.f = x;
  uint32_t r = (v.u + 0x7FFFu + ((v.u >> 16) & 1u)) >> 16;  // RNE
  return (short)r;
}
__device__ __forceinline__ uint32_t rnd_bf_hi(float x) {  // RNE bits, bf16 in high half
  union { float f; uint32_t u; } v; v.f = x;
  return v.u + 0x7FFFu + ((v.u >> 16) & 1u);
}
__device__ __forceinline__ uint32_t pack2bf(float a, float b) {
  // exact RNE pack: D = [bf16(b) : bf16(a)]
  return __builtin_amdgcn_perm(rnd_bf_hi(b), rnd_bf_hi(a), 0x07060302);
}
__device__ __forceinline__ float bfbits2f(uint32_t b16) {
  union { uint32_t u; float f; } v; v.u = b16 << 16; return v.f;
}
__device__ __forceinline__ float fexp2(float x) {
#if __has_builtin(__builtin_amdgcn_exp2f)
  return __builtin_amdgcn_exp2f(x);
#else
  return __expf(x * 0.6931471805599453f);
#endif
}
__device__ __forceinline__ void async16(const void* g, void* l) {
  __builtin_amdgcn_global_load_lds(
      (const __attribute__((address_space(1))) uint32_t*)g,
      (__attribute__((address_space(3))) uint32_t*)l, 16, 0, 0);
}

// ---------- prep: fused fp32->bf16 casts + gates context GEMV ----------
__global__ __launch_bounds__(256) void prep_k(
    const float* __restrict__ x, const float* __restrict__ Wq,
    const float* __restrict__ Wk, const float* __restrict__ Wv,
    const float* __restrict__ Wo, const float* __restrict__ bq,
    short* __restrict__ xb, short* __restrict__ Wqb, short* __restrict__ Wkb,
    short* __restrict__ Wvb, short* __restrict__ Wob, float* __restrict__ ctx) {
  __shared__ float xs[1024];
  const int bid = blockIdx.x;
  const int tid = threadIdx.x;
  if (bid < 8192) {
    const float* src; short* dst; int idx;
    if (bid < 4096) {
      src = x; dst = xb; idx = (bid << 8) + tid;
    } else {
      const int r = bid - 4096;
      const int z = r >> 10;
      src = (z == 0) ? Wq : (z == 1) ? Wk : (z == 2) ? Wv : Wo;
      dst = (z == 0) ? Wqb : (z == 1) ? Wkb : (z == 2) ? Wvb : Wob;
      idx = ((r & 1023) << 8) + tid;
    }
    float4 v = ((const float4*)src)[idx];
    short4 o;
    o.x = f2bf(v.x); o.y = f2bf(v.y); o.z = f2bf(v.z); o.w = f2bf(v.w);
    ((short4*)dst)[idx] = o;
  } else {
    // gates context: ctx[b][n] = x[b,0,:] . Wq[n,:] + bq[n]   (fp32 exact path)
    const int r = bid - 8192;
    const int b = r >> 4;
    const int n0 = (r & 15) << 6;
    for (int i = tid; i < 1024; i += 256) xs[i] = x[b * 1048576 + i];
    __syncthreads();
    const int w = tid >> 6, lane = tid & 63;
    const float4* xv4 = (const float4*)xs;
    for (int rr = 0; rr < 16; ++rr) {
      const int n = n0 + (w << 4) + rr;
      const float4* wrow = (const float4*)(Wq + n * 1024);
      float p = 0.f;
#pragma unroll
      for (int c2 = 0; c2 < 4; ++c2) {
        float4 wv = wrow[lane + (c2 << 6)];
        float4 xv = xv4[lane + (c2 << 6)];
        p += xv.x * wv.x + xv.y * wv.y + xv.z * wv.z + xv.w * wv.w;
      }
#pragma unroll
      for (int off = 32; off; off >>= 1) p += __shfl_xor(p, off);
      if (lane == 0) ctx[b * 1024 + n] = p + bq[n];
    }
  }
}

// ---------- gates finisher: c, scale*log2e, u ----------
__global__ __launch_bounds__(256) void gates_fin(const float* __restrict__ ctx,
                                                 const float* __restrict__ Wg1,
                                                 const float* __restrict__ bg1,
                                                 const float* __restrict__ Wg2,
                                                 const float* __restrict__ bg2,
                                                 float* __restrict__ gates,
                                                 float* __restrict__ u_out) {
  __shared__ float red[16];
  const int tid = threadIdx.x, w = tid >> 6, lane = tid & 63;
  for (int b = 0; b < 4; ++b) {
    float4 cv = ((const float4*)(ctx + b * 1024))[tid];
    float4 w1 = ((const float4*)Wg1)[tid];
    float4 w2 = ((const float4*)Wg2)[tid];
    float p1 = cv.x * w1.x + cv.y * w1.y + cv.z * w1.z + cv.w * w1.w;
    float p2 = cv.x * w2.x + cv.y * w2.y + cv.z * w2.z + cv.w * w2.w;
#pragma unroll
    for (int off = 32; off; off >>= 1) { p1 += __shfl_xor(p1, off); p2 += __shfl_xor(p2, off); }
    if (lane == 0) { red[w] = p1; red[8 + w] = p2; }
    __syncthreads();
    if (tid == 0) {
      float g1 = red[0] + red[1] + red[2] + red[3] + bg1[0];
      float g2 = red[8] + red[9] + red[10] + red[11] + bg2[0];
      float q1 = 1.f / (1.f + expf(-g1));
      float q2 = 1.f / (1.f + expf(-g2));
      float c = fminf(fmaxf(q1 * q2, 1e-8f), 1.0f);
      gates[b * 2 + 0] = c;
      // (1/(sqrt(64)*tau)) * log2(e), applied to raw scores inside attn
      gates[b * 2 + 1] = (c < 0.3f ? c : 1.0f) * 0.125f * 1.4426950408889634f;
      u_out[b] = 1.0f - c;
    }
    __syncthreads();
  }
}

// ---------- QKV projection GEMM: R2/R7 structure (measured optimum) ----------
// 128x128 tile, BK=32, 2-barrier K-loop, non-swizzled LDS, scatter epilogues.
// Design space swept: dbuf(R3), 64-tile(R6), swizzle(R5), BK=64(R10),
// kv/epilogue variants — all neutral or worse. Do not touch.
// C[m,n] = sum_k xb[m,k]*W[n,k] + bias[n];  z=0:Q  z=1:K  z=2:V^T [BH][64][T]
__global__ __launch_bounds__(256) void gemm_qkv(
    const short* __restrict__ xb,
    const short* __restrict__ Wqb, const short* __restrict__ Wkb, const short* __restrict__ Wvb,
    const float* __restrict__ bq, const float* __restrict__ bk, const float* __restrict__ bv,
    short* __restrict__ Qh, short* __restrict__ Kh, short* __restrict__ Vt) {
  const int z = blockIdx.z;
  const short* W = (z == 0) ? Wqb : (z == 1) ? Wkb : Wvb;
  const float* bias = (z == 0) ? bq : (z == 1) ? bk : bv;

  const int m0 = blockIdx.x << 7;
  const int n0 = blockIdx.y << 7;
  const int tid = threadIdx.x;
  const int w = tid >> 6, lane = tid & 63;
  const int m15 = lane & 15, quad = lane >> 4;
  const int wr = w >> 1, wc = w & 1;

  __shared__ short As[4096];
  __shared__ short Bs[4096];

  f32x4 acc[4][4];
#pragma unroll
  for (int i = 0; i < 4; ++i)
#pragma unroll
    for (int j = 0; j < 4; ++j) { f32x4 zz = {0.f, 0.f, 0.f, 0.f}; acc[i][j] = zz; }

  const int srow = (w << 5) + (lane >> 2);
  const int scol = (lane & 3) << 3;
  const short* ga0 = xb + (m0 + srow) * 1024 + scol;
  const short* ga1 = ga0 + 16 * 1024;
  const short* gb0 = W + (n0 + srow) * 1024 + scol;
  const short* gb1 = gb0 + 16 * 1024;
  short* la0 = &As[srow * 32 + scol];
  short* la1 = la0 + 512;
  short* lb0 = &Bs[srow * 32 + scol];
  short* lb1 = lb0 + 512;

  for (int kt = 0; kt < 32; ++kt) {
    async16(ga0, la0); async16(ga1, la1);
    async16(gb0, lb0); async16(gb1, lb1);
    ga0 += 32; ga1 += 32; gb0 += 32; gb1 += 32;
    __syncthreads();
    bf16x8 a[4], b[4];
#pragma unroll
    for (int i = 0; i < 4; ++i)
      a[i] = *(const bf16x8*)(&As[((wr << 6) + (i << 4) + m15) * 32 + (quad << 3)]);
#pragma unroll
    for (int j = 0; j < 4; ++j)
      b[j] = *(const bf16x8*)(&Bs[((wc << 6) + (j << 4) + m15) * 32 + (quad << 3)]);
#pragma unroll
    for (int i = 0; i < 4; ++i)
#pragma unroll
      for (int j = 0; j < 4; ++j)
        acc[i][j] = MFMA_BF16(a[i], b[j], acc[i][j]);
    __syncthreads();
  }

#pragma unroll
  for (int j = 0; j < 4; ++j) {
    const int n = n0 + (wc << 6) + (j << 4) + m15;
    const float bb_ = bias[n];
    const int h = n >> 6, dk = n & 63;
#pragma unroll
    for (int i = 0; i < 4; ++i) {
      const int mb = m0 + (wr << 6) + (i << 4) + (quad << 2);
#pragma unroll
      for (int r = 0; r < 4; ++r) {
        const int m = mb + r;
        const int batch = m >> 10, t = m & 1023;
        const short o = f2bf(acc[i][j][r] + bb_);
        if (z == 2) {
          Vt[((batch * 16 + h) * 64 + dk) * 1024 + t] = o;        // [BH][64][T]
        } else if (z == 1) {
          Kh[((batch * 16 + h) * 1024 + t) * 64 + dk] = o;        // [BH][T][64]
        } else {
          Qh[((batch * 16 + h) * 1024 + t) * 64 + dk] = o;
        }
      }
    }
  }
}

// ---------- output projection GEMM: 64x128, m97 2-barrier, swizzled, fp32 out ----------
__global__ __launch_bounds__(256) void gemm_out(const short* __restrict__ Ab,
                                                const short* __restrict__ Wo,
                                                const float* __restrict__ bo,
                                                float* __restrict__ Cout) {
  const int m0 = blockIdx.x << 6;
  const int n0 = blockIdx.y << 7;
  const int tid = threadIdx.x;
  const int w = tid >> 6, lane = tid & 63;
  const int m15 = lane & 15, quad = lane >> 4;
  const int wr = w >> 1, wc = w & 1;

  __shared__ short As[2048];   // 64 x 32, swizzled
  __shared__ short Bs[4096];   // 128 x 32, swizzled

  f32x4 acc[2][4];
#pragma unroll
  for (int i = 0; i < 2; ++i)
#pragma unroll
    for (int j = 0; j < 4; ++j) { f32x4 zz = {0.f, 0.f, 0.f, 0.f}; acc[i][j] = zz; }

  const int s0 = tid, s1 = tid + 256;
  const int arow = s0 >> 2, alcb = (s0 & 3) ^ ((arow >> 1) & 3);
  const int brow1 = s1 >> 2, blcb1 = (s1 & 3) ^ ((brow1 >> 1) & 3);
  const short* gA  = Ab + (m0 + arow) * 1024 + (alcb << 3);
  const short* gB0 = Wo + (n0 + arow) * 1024 + (alcb << 3);
  const short* gB1 = Wo + (n0 + brow1) * 1024 + (blcb1 << 3);
  short* lA  = &As[s0 << 3];
  short* lB0 = &Bs[s0 << 3];
  short* lB1 = &Bs[s1 << 3];

  for (int kt = 0; kt < 32; ++kt) {
    async16(gA, lA);
    async16(gB0, lB0); async16(gB1, lB1);
    gA += 32; gB0 += 32; gB1 += 32;
    __syncthreads();
    bf16x8 a[2], b[4];
#pragma unroll
    for (int i = 0; i < 2; ++i) {
      const int ra = (wr << 5) + (i << 4) + m15;
      a[i] = *(const bf16x8*)(&As[ra * 32 + ((quad ^ ((ra >> 1) & 3)) << 3)]);
    }
#pragma unroll
    for (int j = 0; j < 4; ++j) {
      const int rb = (wc << 6) + (j << 4) + m15;
      b[j] = *(const bf16x8*)(&Bs[rb * 32 + ((quad ^ ((rb >> 1) & 3)) << 3)]);
    }
#pragma unroll
    for (int i = 0; i < 2; ++i)
#pragma unroll
      for (int j = 0; j < 4; ++j)
        acc[i][j] = MFMA_BF16(a[i], b[j], acc[i][j]);
    __syncthreads();
  }

#pragma unroll
  for (int j = 0; j < 4; ++j) {
    const int n = n0 + (wc << 6) + (j << 4) + m15;
    const float bb_ = bo[n];
#pragma unroll
    for (int i = 0; i < 2; ++i) {
      const int mb = m0 + (wr << 5) + (i << 4) + (quad << 2);
#pragma unroll
      for (int r = 0; r < 4; ++r)
        Cout[(mb + r) * 1024 + n] = acc[i][j][r] + bb_;
    }
  }
}

// ---------- meanV over keys: mV[bh][d] = sum_t Vt[bh][d][t]  (raw sum) ----------
__global__ __launch_bounds__(256) void meanv_k(const short* __restrict__ Vt,
                                               float* __restrict__ mV) {
  const int bh = blockIdx.x;
  const int tid = threadIdx.x;
  const int d = tid >> 2, part = tid & 3;
  const short* row = Vt + bh * 65536 + d * 1024 + part * 256;
  float s = 0.f;
#pragma unroll 4
  for (int i = 0; i < 64; ++i) {
    uint2 v = *(const uint2*)(row + i * 4);
    s += bfbits2f(v.x & 0xffffu) + bfbits2f(v.x >> 16) +
         bfbits2f(v.y & 0xffffu) + bfbits2f(v.y >> 16);
  }
  s += __shfl_xor(s, 1);
  s += __shfl_xor(s, 2);
  if (part == 0) mV[bh * 64 + d] = s;
}

// ---------- flash attention, transposed-S formulation (R7, measured best) ----------
// S^T = K*Q'^T; p = exp2(S^T * sl) lane-local (sl = scale*log2e);
// O^T = V^T * P; no max-tracking (|S*sl| bounded ~8), l reduced once at end.
__global__ __launch_bounds__(256, 4) void attn_k(const short* __restrict__ Qh,
                                                 const short* __restrict__ Kh,
                                                 const short* __restrict__ Vt,
                                                 const float* __restrict__ gates,
                                                 const float* __restrict__ mV,
                                                 short* __restrict__ attnb) {
  const int bh = blockIdx.x;
  const int b = bh >> 4, h = bh & 15;
  const int q0 = blockIdx.y << 6;
  const int tid = threadIdx.x;
  const int w = tid >> 6, lane = tid & 63;
  const int m15 = lane & 15, quad = lane >> 4;

  __shared__ short Ks[2][4096];  // [64 k][64 d], 8-short blocks XOR-swizzled by row&7
  __shared__ short Vs[2][4096];  // [64 d][64 t], same swizzle

  const short* ksrc = Kh + bh * 65536;
  const short* vsrc = Vt + bh * 65536;

  const float sl = gates[b * 2 + 1];

  // hoisted Q B-fragments (wave's 16 q-cols, loop-invariant)
  const short* qsrc = Qh + ((bh << 10) + q0 + (w << 4) + m15) * 64;
  const bf16x8 qb0 = *(const bf16x8*)(qsrc + (quad << 3));
  const bf16x8 qb1 = *(const bf16x8*)(qsrc + 32 + (quad << 3));

  // staging addresses (lane-linear LDS dest as global_load_lds requires)
  const int off0 = tid, off1 = tid + 256;
  const int r0 = off0 >> 3, cb0 = (off0 & 7) ^ (r0 & 7);
  const int r1 = off1 >> 3, cb1 = (off1 & 7) ^ (r1 & 7);

#define STAGE(kv, bufi)                                                        \
  do {                                                                         \
    async16(ksrc + (((kv) << 6) + r0) * 64 + (cb0 << 3), &Ks[bufi][off0 << 3]);\
    async16(ksrc + (((kv) << 6) + r1) * 64 + (cb1 << 3), &Ks[bufi][off1 << 3]);\
    async16(vsrc + r0 * 1024 + ((kv) << 6) + (cb0 << 3), &Vs[bufi][off0 << 3]);\
    async16(vsrc + r1 * 1024 + ((kv) << 6) + (cb1 << 3), &Vs[bufi][off1 << 3]);\
  } while (0)

  STAGE(0, 0);

  float lsum = 0.f;
  f32x4 o_acc[4];
#pragma unroll
  for (int jd = 0; jd < 4; ++jd) { f32x4 zz = {0.f, 0.f, 0.f, 0.f}; o_acc[jd] = zz; }

  const int srcA = ((quad & 1) << 5) + m15;  // source quad 2*(qt&1)
  const int srcB = srcA + 16;                // source quad 2*(qt&1)+1
  const bool selhi = (quad & 2) != 0;        // s = 2H + (quad>>1)

  for (int kv = 0; kv < 16; ++kv) {
    __syncthreads();  // drains STAGE(kv) (vmcnt) and prior iter's frag reads
    if (kv < 15) STAGE(kv + 1, (kv + 1) & 1);
    const short* Kb = &Ks[kv & 1][0];
    const short* Vb = &Vs[kv & 1][0];

    // S^T tile: lane holds (q = w*16+m15, k = kv*64 + s*16 + quad*4 + r)
    f32x4 sacc[4];
#pragma unroll
    for (int s = 0; s < 4; ++s) {
      const int row = (s << 4) + m15;
      const int sw = row & 7;
      bf16x8 a0 = *(const bf16x8*)(Kb + (row << 6) + ((quad ^ sw) << 3));
      bf16x8 a1 = *(const bf16x8*)(Kb + (row << 6) + (((quad + 4) ^ sw) << 3));
      f32x4 zz = {0.f, 0.f, 0.f, 0.f};
      zz = MFMA_BF16(a0, qb0, zz);
      zz = MFMA_BF16(a1, qb1, zz);
      sacc[s] = zz;
    }

    // lane-local softmax numerators + packed bf16 pairs (exact RNE)
    uint32_t pk[4][2];
#pragma unroll
    for (int s = 0; s < 4; ++s) {
      float p0 = fexp2(sacc[s][0] * sl);
      float p1 = fexp2(sacc[s][1] * sl);
      float p2 = fexp2(sacc[s][2] * sl);
      float p3 = fexp2(sacc[s][3] * sl);
      lsum += (p0 + p1) + (p2 + p3);
      pk[s][0] = pack2bf(p0, p1);
      pk[s][1] = pack2bf(p2, p3);
    }

    // build P B-fragments: lane n=q needs k = H*32 + quad*8 + j
    bf16x8 pf[2];
#pragma unroll
    for (int H = 0; H < 2; ++H) {
      uint32_t f[4];
#pragma unroll
      for (int rp = 0; rp < 2; ++rp) {
        uint32_t alo = (uint32_t)__shfl((int)pk[2 * H][rp], srcA);
        uint32_t ahi = (uint32_t)__shfl((int)pk[2 * H + 1][rp], srcA);
        uint32_t blo = (uint32_t)__shfl((int)pk[2 * H][rp], srcB);
        uint32_t bhi = (uint32_t)__shfl((int)pk[2 * H + 1][rp], srcB);
        f[rp]     = selhi ? ahi : alo;
        f[2 + rp] = selhi ? bhi : blo;
      }
      pf[H] = *(bf16x8*)f;
    }

    // O^T += V^T * P
#pragma unroll
    for (int jd = 0; jd < 4; ++jd) {
      const int row = (jd << 4) + m15;
      const int sw = row & 7;
      bf16x8 v0 = *(const bf16x8*)(Vb + (row << 6) + ((quad ^ sw) << 3));
      bf16x8 v1 = *(const bf16x8*)(Vb + (row << 6) + (((quad + 4) ^ sw) << 3));
      o_acc[jd] = MFMA_BF16(v0, pf[0], o_acc[jd]);
      o_acc[jd] = MFMA_BF16(v1, pf[1], o_acc[jd]);
    }
  }
#undef STAGE

  // finish l(q): lane's partial covers its (quad,s,r) k-subset; reduce over quads
  float l = lsum;
  l += __shfl_xor(l, 16);
  l += __shfl_xor(l, 32);

  const float cg = gates[b * 2 + 0];
  const float s0 = cg / l;
  const float coef = (1.0f - cg) * (1.0f / 1024.0f);  // mV holds raw sums over t
  const int qrow = q0 + (w << 4) + m15;
  short* orow = attnb + ((b << 10) + qrow) * 1024 + (h << 6);
#pragma unroll
  for (int jd = 0; jd < 4; ++jd) {
    float4 mv = *(const float4*)(mV + (bh << 6) + (jd << 4) + (quad << 2));
    float v0_ = s0 * o_acc[jd][0] + coef * mv.x;
    float v1_ = s0 * o_acc[jd][1] + coef * mv.y;
    float v2_ = s0 * o_acc[jd][2] + coef * mv.z;
    float v3_ = s0 * o_acc[jd][3] + coef * mv.w;
    uint2 st;
    st.x = pack2bf(v0_, v1_);
    st.y = pack2bf(v2_, v3_);
    *(uint2*)(orow + (jd << 4) + (quad << 2)) = st;
  }
}

// ---------- launch ----------
extern "C" void kernel_launch(void* const* d_in, const int* in_sizes, int n_in,
                              void* d_out, int out_size, void* d_ws, size_t ws_size,
                              hipStream_t stream) {
  const float* x   = (const float*)d_in[0];
  const float* Wq  = (const float*)d_in[1];
  const float* bq  = (const float*)d_in[2];
  const float* Wk  = (const float*)d_in[3];
  const float* bk  = (const float*)d_in[4];
  const float* Wv  = (const float*)d_in[5];
  const float* bv  = (const float*)d_in[6];
  const float* Wo  = (const float*)d_in[7];
  const float* bo  = (const float*)d_in[8];
  const float* Wg1 = (const float*)d_in[9];
  const float* bg1 = (const float*)d_in[10];
  const float* Wg2 = (const float*)d_in[11];
  const float* bg2 = (const float*)d_in[12];
  float* out = (float*)d_out;

  char* ws = (char*)d_ws;
  short* xb   = (short*)(ws + 0);          //  8 MB  x bf16 [4096][1024]
  short* Wqb  = (short*)(ws + 8388608);    //  2 MB
  short* Wkb  = (short*)(ws + 10485760);   //  2 MB
  short* Wvb  = (short*)(ws + 12582912);   //  2 MB
  short* Wob  = (short*)(ws + 14680064);   //  2 MB
  short* Qh   = (short*)(ws + 16777216);   //  8 MB  [BH][T][64]
  short* Kh   = (short*)(ws + 25165824);   //  8 MB  [BH][T][64]
  short* Vt   = (short*)(ws + 33554432);   //  8 MB  [BH][64][T]
  short* attb = (short*)(ws + 41943040);   //  8 MB  [4096][1024]
  float* ctx  = (float*)(ws + 50331648);   // 16 KB
  float* gat  = (float*)(ws + 50348032);   // 32 B   [B][{c, scale*log2e}]
  float* mV   = (float*)(ws + 50348064);   // 16 KB  [BH][64] raw sums

  prep_k<<<8256, 256, 0, stream>>>(x, Wq, Wk, Wv, Wo, bq,
                                   xb, Wqb, Wkb, Wvb, Wob, ctx);
  gates_fin<<<1, 256, 0, stream>>>(ctx, Wg1, bg1, Wg2, bg2, gat, out + 4194304);

  gemm_qkv<<<dim3(32, 8, 3), 256, 0, stream>>>(xb, Wqb, Wkb, Wvb, bq, bk, bv,
                                               Qh, Kh, Vt);
  meanv_k<<<64, 256, 0, stream>>>(Vt, mV);
  attn_k<<<dim3(64, 16), 256, 0, stream>>>(Qh, Kh, Vt, gat, mV, attb);
  gemm_out<<<dim3(64, 8), 256, 0, stream>>>(attb, Wob, bo, out);
}